// Round 21
// baseline (185.593 us; speedup 1.0000x reference)
//
#include <hip/hip_runtime.h>
#include <math.h>

#define B_ 4
#define S_ 2048
#define D_ 1024
#define H_ 16
#define DK_ 64
#define SCALE_ 0.125f
#define THETA_ 10000.0f
#define LOG2E_ 1.44269504f
#define THR_ 8.0f

typedef unsigned short ushort_t;
typedef __attribute__((ext_vector_type(8))) short bf16x8;   // 8 bf16 (4 VGPRs)
typedef __attribute__((ext_vector_type(4))) float f32x4;    // MFMA C/D

__device__ __forceinline__ ushort_t f2bf(float f) {
    union { float f; unsigned u; } v; v.f = f;
    unsigned r = (v.u + 0x7FFFu + ((v.u >> 16) & 1u)) >> 16;   // RNE
    return (ushort_t)r;
}

// pack bf16(lo),bf16(hi) by TRUNCATION: 1 v_perm_b32
__device__ __forceinline__ unsigned permpk(float lo, float hi) {
    return __builtin_amdgcn_perm(__float_as_uint(hi), __float_as_uint(lo), 0x07060302u);
}

// row swizzle incl. bit3 (breaks lr / lr+8 bank aliasing): bijective XOR/row
__device__ __forceinline__ int rswz(int row) {
    return (row & 7) ^ (((row >> 3) & 1) << 2);
}

// Vt swizzle (row in 0..63): unchanged (already 4-way)
__device__ __forceinline__ int vswz(int row) { return (row & 7) ^ ((row >> 3) & 3); }

#define GLOAD_LDS16(gptr, lptr)                                                   \
    __builtin_amdgcn_global_load_lds(                                             \
        (const __attribute__((address_space(1))) unsigned int*)(gptr),            \
        (__attribute__((address_space(3))) unsigned int*)(lptr), 16, 0, 0)

// ---------------------------------------------------------------------------
// Fused prep: fp32->bf16 casts (x + 4 weights) + RoPE table, one dispatch.
// ---------------------------------------------------------------------------
__global__ __launch_bounds__(256) void cast_all(const float* __restrict__ x,
                                                const float* __restrict__ W0,
                                                const float* __restrict__ W1,
                                                const float* __restrict__ W2,
                                                const float* __restrict__ W3,
                                                const int* __restrict__ pos,
                                                ushort_t* __restrict__ Xb,
                                                ushort_t* __restrict__ Wb,
                                                float2* __restrict__ tab) {
    const int bid = blockIdx.x;
    if (bid >= 12288) {                       // rope table
        int i = (bid - 12288) * 256 + threadIdx.x;   // 0..65535
        int s = i >> 5, p = i & 31;
        float freq = powf(THETA_, -2.0f * (float)p / 64.0f);
        float a = (float)pos[s] * freq;
        tab[i] = make_float2(cosf(a), sinf(a));
        return;
    }
    const float* src;
    ushort_t* dst;
    int i;
    if (bid < 8192) {
        src = x; dst = Xb;
        i = bid * 1024 + threadIdx.x * 4;
    } else {
        const int seg = (bid - 8192) >> 10;          // 0..3
        const int lb  = (bid - 8192) & 1023;
        src = (seg == 0) ? W0 : (seg == 1) ? W1 : (seg == 2) ? W2 : W3;
        dst = Wb + (size_t)seg * (D_ * D_);
        i = lb * 1024 + threadIdx.x * 4;
    }
    float4 v = *reinterpret_cast<const float4*>(src + i);
    unsigned lo = (unsigned)f2bf(v.x) | ((unsigned)f2bf(v.y) << 16);
    unsigned hi = (unsigned)f2bf(v.z) | ((unsigned)f2bf(v.w) << 16);
    uint2 u; u.x = lo; u.y = hi;
    *reinterpret_cast<uint2*>(dst + i) = u;
}

// ---------------------------------------------------------------------------
// bf16 MFMA GEMM, BK=64 + swizzled K-staging. R16 structure; staging/read
// swizzle now includes row bit3 (rswz) to break lr/lr+8 bank aliasing.
// MODE 0: fp32 Y[m*D+n]  MODE 1: bf16 Y[b,h,s,dk]  MODE 2: MODE1 + RoPE*qscale
// ---------------------------------------------------------------------------
template <int MODE>
__global__ __launch_bounds__(256) void gemm_bf16(const ushort_t* __restrict__ A,
                                                 const ushort_t* __restrict__ W,
                                                 const float2* __restrict__ tab,
                                                 float qscale,
                                                 float* __restrict__ outF,
                                                 ushort_t* __restrict__ outB) {
    __shared__ ushort_t Asl[128 * 64];
    __shared__ ushort_t Bsl[128 * 64];

    const int t = threadIdx.x;
    const int lane = t & 63;
    const int w = t >> 6;
    const int lr = lane & 15;
    const int lg = lane >> 4;

    const int bid = blockIdx.x;
    const int swz = (bid & 7) * 64 + (bid >> 3);
    const int m0 = (swz >> 3) * 128;
    const int n0 = (swz & 7) * 128;

    const int wr = w >> 1;
    const int wc = w & 1;

    f32x4 acc[4][4] = {};

    for (int k0 = 0; k0 < D_; k0 += 64) {
#pragma unroll
        for (int it = 0; it < 4; ++it) {
            const int slot = it * 256 + t;
            const int row = slot >> 3;
            const int cs = (slot & 7) ^ rswz(row);
            GLOAD_LDS16(A + (size_t)(m0 + row) * D_ + k0 + cs * 8, Asl + slot * 8);
            GLOAD_LDS16(W + (size_t)(n0 + row) * D_ + k0 + cs * 8, Bsl + slot * 8);
        }
        __syncthreads();

#pragma unroll
        for (int kk = 0; kk < 2; ++kk) {
            bf16x8 af[4], bfr[4];
#pragma unroll
            for (int x = 0; x < 4; ++x) {
                const int ra = wr * 64 + x * 16 + lr;        // rswz(ra) = rswz-of-lr bits
                const int rb = wc * 64 + x * 16 + lr;
                const int ch = (kk * 4 + lg) ^ rswz(ra);     // ra,rb share low 4 bits = lr
                af[x]  = *reinterpret_cast<const bf16x8*>((char*)Asl + ra * 128 + (ch << 4));
                bfr[x] = *reinterpret_cast<const bf16x8*>((char*)Bsl + rb * 128 + (ch << 4));
            }
#pragma unroll
            for (int mi = 0; mi < 4; ++mi)
#pragma unroll
                for (int ni = 0; ni < 4; ++ni)
                    acc[mi][ni] = __builtin_amdgcn_mfma_f32_16x16x32_bf16(af[mi], bfr[ni], acc[mi][ni], 0, 0, 0);
        }
        __syncthreads();
    }

#pragma unroll
    for (int mi = 0; mi < 4; ++mi) {
#pragma unroll
        for (int r = 0; r < 4; ++r) {
            const int m = m0 + wr * 64 + mi * 16 + lg * 4 + r;
            const int bb = m >> 11;
            const int s = m & (S_ - 1);
#pragma unroll
            for (int ni = 0; ni < 4; ++ni) {
                const int n = n0 + wc * 64 + ni * 16 + lr;
                float v = acc[mi][ni][r];
                if (MODE == 0) {
                    outF[(size_t)m * D_ + n] = v;
                } else {
                    const int h = n >> 6, dk = n & 63;
                    if (MODE == 2) {
                        v *= qscale;
                        const float2 cs = tab[s * 32 + (dk >> 1)];
                        const float part = __shfl_xor(v, 1, 64);
                        v = (dk & 1) ? fmaf(v, cs.x, part * cs.y)
                                     : fmaf(v, cs.x, -part * cs.y);
                    }
                    outB[(((size_t)bb * H_ + h) * S_ + s) * DK_ + dk] = f2bf(v);
                }
            }
        }
    }
}

// ---------------------------------------------------------------------------
// MFMA flash attention v13 (causal). R18 single-barrier structure; Ks and Pl
// swizzles now include row bit3 (rswz) -> lr/lr+8 no longer share bank groups
// (8-way -> 4-way on kb/pfr reads). Vt unchanged (already 4-way).
// ---------------------------------------------------------------------------
__global__ __launch_bounds__(512) void attn_mfma(const ushort_t* __restrict__ Q,
                                                 const ushort_t* __restrict__ K,
                                                 const ushort_t* __restrict__ V,
                                                 ushort_t* __restrict__ O) {
    __shared__ ushort_t Ks[2][64 * 64];
    __shared__ ushort_t Vt[2][64 * 64];
    __shared__ ushort_t Pl[128 * 64];

    const int t = threadIdx.x;
    const int lane = t & 63;
    const int w = t >> 6;           // 0..7
    const int lr = lane & 15;
    const int lg = lane >> 4;

    const int bid = blockIdx.x;
    const int swz = (bid & 7) * 64 + (bid >> 3);
    const int bh = swz >> 3;
    const int p  = swz & 7;

    const ushort_t* Kbase = K + (size_t)bh * S_ * DK_;
    const ushort_t* Vbase = V + (size_t)bh * S_ * DK_;
    const int bb = bh >> 4, h = bh & 15;

    const int krow = t >> 3;                 // 0..63
    const int kc16 = (t & 7) ^ rswz(krow);
    const int dk8 = (t & 7) * 8;
    const int kv2 = ((t >> 3) & 31) * 2;

    // per-lane read swizzle: row low-4 bits are lr for all kb/pfr rows
    const int rs = rswz(lr);

    bf16x8 ones;
#pragma unroll
    for (int j = 0; j < 8; ++j) ones[j] = (short)0x3F80;

    bf16x8 vpre0, vpre1;
    int kcur = 0;

    for (int ph = 0; ph < 2; ++ph) {
        const int qt = ph ? (15 - p) : p;
        const int q0 = qt * 128;
        const int nt = 2 * qt + 2;          // always even

        const ushort_t* Qbase = Q + ((size_t)bh * S_ + q0 + w * 16) * DK_;
        bf16x8 qf[2];
#pragma unroll
        for (int kf = 0; kf < 2; ++kf)
            qf[kf] = *reinterpret_cast<const bf16x8*>(
                Qbase + (size_t)lr * DK_ + kf * 32 + lg * 8);

        f32x4 acc[4] = {};
        f32x4 accl = {};
        float mrow = -INFINITY;

        // ---- prologue: K(0) -> Ks[kcur]; V(0) -> regs; drain + phase fence ----
        GLOAD_LDS16(Kbase + (size_t)krow * DK_ + kc16 * 8, &Ks[kcur][t * 8]);
        if (t < 256) {
            const ushort_t* Vsrc = Vbase + (size_t)kv2 * DK_ + dk8;
            vpre0 = *reinterpret_cast<const bf16x8*>(Vsrc);
            vpre1 = *reinterpret_cast<const bf16x8*>(Vsrc + DK_);
        }
        __syncthreads();

        for (int kt = 0; kt < nt; ++kt) {
            const int vcur = kt & 1;

            // ---- write V(kt) regs -> Vt[vcur] (transposed, swizzled) ----
            if (t < 256) {
                const unsigned* aw = reinterpret_cast<const unsigned*>(&vpre0);
                const unsigned* bw = reinterpret_cast<const unsigned*>(&vpre1);
#pragma unroll
                for (int j = 0; j < 8; ++j) {
                    const int row = dk8 + j;
                    const unsigned sel = (j & 1) ? 0x07060302u : 0x05040100u;
                    const unsigned pk = __builtin_amdgcn_perm(bw[j >> 1], aw[j >> 1], sel);
                    *reinterpret_cast<unsigned*>(
                        (char*)Vt[vcur] + row * 128 + ((kv2 * 2) ^ (vswz(row) << 4))) = pk;
                }
            }
            __syncthreads();    // THE barrier: publishes Vt[vcur]+drains K(kt)

            // ---- prefetches (in flight until next barrier) ----
            if (kt + 1 < nt) {
                const ushort_t* Ksrc = Kbase + (size_t)(kt + 1) * 64 * DK_;
                GLOAD_LDS16(Ksrc + (size_t)krow * DK_ + kc16 * 8, &Ks[kcur ^ 1][t * 8]);
                if (t < 256) {
                    const ushort_t* Vsrc = Vbase + (size_t)((kt + 1) * 64 + kv2) * DK_ + dk8;
                    vpre0 = *reinterpret_cast<const bf16x8*>(Vsrc);
                    vpre1 = *reinterpret_cast<const bf16x8*>(Vsrc + DK_);
                }
            }

            // ---- sT = K Q ----
            bf16x8 kb[4][2];
#pragma unroll
            for (int nf = 0; nf < 4; ++nf)
#pragma unroll
                for (int kf = 0; kf < 2; ++kf)
                    kb[nf][kf] = *reinterpret_cast<const bf16x8*>(
                        (char*)Ks[kcur] + (nf * 16 + lr) * 128 + (((kf * 4 + lg) ^ rs) << 4));

            f32x4 sT[4];
#pragma unroll
            for (int nf = 0; nf < 4; ++nf) {
                f32x4 z = {};
                z = __builtin_amdgcn_mfma_f32_16x16x32_bf16(kb[nf][0], qf[0], z, 0, 0, 0);
                z = __builtin_amdgcn_mfma_f32_16x16x32_bf16(kb[nf][1], qf[1], z, 0, 0, 0);
                sT[nf] = z;
            }

            if (kt >= nt - 2) {
                const int q = q0 + w * 16 + lr;
#pragma unroll
                for (int nf = 0; nf < 4; ++nf)
#pragma unroll
                    for (int r = 0; r < 4; ++r) {
                        const int kv = kt * 64 + nf * 16 + lg * 4 + r;
                        if (kv > q) sT[nf][r] = -INFINITY;
                    }
            }

            {
                float m4 = -INFINITY;
#pragma unroll
                for (int nf = 0; nf < 4; ++nf)
#pragma unroll
                    for (int r = 0; r < 4; ++r) m4 = fmaxf(m4, sT[nf][r]);
                m4 = fmaxf(m4, __shfl_xor(m4, 16, 64));
                m4 = fmaxf(m4, __shfl_xor(m4, 32, 64));
                if (m4 > mrow + THR_) {
                    const float corr = __builtin_amdgcn_exp2f(mrow - m4);
                    mrow = m4;
#pragma unroll
                    for (int r = 0; r < 4; ++r) accl[r] *= corr;
#pragma unroll
                    for (int df = 0; df < 4; ++df)
#pragma unroll
                        for (int r = 0; r < 4; ++r) acc[df][r] *= corr;
                }
            }

            const int prow = w * 16 + lr;
            char* prowp = (char*)Pl + prow * 128;
#pragma unroll
            for (int nf = 0; nf < 4; ++nf) {
                const float p0 = __builtin_amdgcn_exp2f(sT[nf][0] - mrow);
                const float p1 = __builtin_amdgcn_exp2f(sT[nf][1] - mrow);
                const float p2 = __builtin_amdgcn_exp2f(sT[nf][2] - mrow);
                const float p3 = __builtin_amdgcn_exp2f(sT[nf][3] - mrow);
                uint2 pk;
                pk.x = permpk(p0, p1);
                pk.y = permpk(p2, p3);
                const int chunk = (nf * 2 + (lg >> 1)) ^ rs;
                *reinterpret_cast<uint2*>(prowp + (chunk << 4) + (lg & 1) * 8) = pk;
            }

            bf16x8 pfr[2];
#pragma unroll
            for (int kf = 0; kf < 2; ++kf)
                pfr[kf] = *reinterpret_cast<const bf16x8*>(
                    (char*)Pl + prow * 128 + (((kf * 4 + lg) ^ rs) << 4));

            bf16x8 vtf[4][2];
#pragma unroll
            for (int df = 0; df < 4; ++df)
#pragma unroll
                for (int kf = 0; kf < 2; ++kf)
                    vtf[df][kf] = *reinterpret_cast<const bf16x8*>(
                        (char*)Vt[vcur] + (df * 16 + lr) * 128 + (((kf * 4 + lg) ^ vswz(df * 16 + lr)) << 4));

#pragma unroll
            for (int kf = 0; kf < 2; ++kf)
                accl = __builtin_amdgcn_mfma_f32_16x16x32_bf16(ones, pfr[kf], accl, 0, 0, 0);
#pragma unroll
            for (int df = 0; df < 4; ++df)
#pragma unroll
                for (int kf = 0; kf < 2; ++kf)
                    acc[df] = __builtin_amdgcn_mfma_f32_16x16x32_bf16(vtf[df][kf], pfr[kf], acc[df], 0, 0, 0);

            kcur ^= 1;          // no end-of-tile barrier (Vt dbuf + next B1)
        }
        kcur = 0;

        const float inv = 1.0f / accl[0];
        const int q = q0 + w * 16 + lr;
        ushort_t* Orow = O + ((size_t)bb * S_ + q) * D_ + h * DK_;
#pragma unroll
        for (int df = 0; df < 4; ++df) {
            unsigned lo = (unsigned)f2bf(acc[df][0] * inv) | ((unsigned)f2bf(acc[df][1] * inv) << 16);
            unsigned hi = (unsigned)f2bf(acc[df][2] * inv) | ((unsigned)f2bf(acc[df][3] * inv) << 16);
            *reinterpret_cast<unsigned*>(Orow + df * 16 + lg * 4)     = lo;
            *reinterpret_cast<unsigned*>(Orow + df * 16 + lg * 4 + 2) = hi;
        }
    }
}

// ---------------------------------------------------------------------------
// Launch: 6 dispatches
// ---------------------------------------------------------------------------
extern "C" void kernel_launch(void* const* d_in, const int* in_sizes, int n_in,
                              void* d_out, int out_size, void* d_ws, size_t ws_size,
                              hipStream_t stream) {
    const float* x  = (const float*)d_in[0];
    const int*   tp = (const int*)d_in[1];
    const float* Wq = (const float*)d_in[2];
    const float* Wk = (const float*)d_in[3];
    const float* Wv = (const float*)d_in[4];
    const float* Wo = (const float*)d_in[5];
    float* out = (float*)d_out;

    char* ws = (char*)d_ws;
    ushort_t* Xb  = (ushort_t*)(ws);
    ushort_t* Wqb = (ushort_t*)(ws + (16ull << 20));   // Wq|Wk|Wv|Wo contiguous
    ushort_t* Wkb = (ushort_t*)(ws + (18ull << 20));
    ushort_t* Wvb = (ushort_t*)(ws + (20ull << 20));
    ushort_t* Wob = (ushort_t*)(ws + (22ull << 20));
    ushort_t* Qb  = (ushort_t*)(ws + (24ull << 20));
    ushort_t* Kb  = (ushort_t*)(ws + (40ull << 20));
    ushort_t* Vb  = (ushort_t*)(ws + (56ull << 20));
    ushort_t* Ao  = (ushort_t*)(ws + (72ull << 20));
    float2*   tab = (float2*)(ws + (88ull << 20));

    cast_all<<<8192 + 4096 + 256, 256, 0, stream>>>(x, Wq, Wk, Wv, Wo, tp, Xb, Wqb, tab);

    gemm_bf16<2><<<512, 256, 0, stream>>>(Xb, Wqb, tab, SCALE_ * LOG2E_, nullptr, Qb);
    gemm_bf16<2><<<512, 256, 0, stream>>>(Xb, Wkb, tab, 1.0f, nullptr, Kb);
    gemm_bf16<1><<<512, 256, 0, stream>>>(Xb, Wvb, tab, 1.0f, nullptr, Vb);

    attn_mfma<<<512, 512, 0, stream>>>(Qb, Kb, Vb, Ao);

    gemm_bf16<0><<<512, 256, 0, stream>>>(Ao, Wob, tab, 1.0f, out, nullptr);
}

// Round 22
// 178.136 us; speedup vs baseline: 1.0419x; 1.0419x over previous
//
#include <hip/hip_runtime.h>
#include <math.h>

#define B_ 4
#define S_ 2048
#define D_ 1024
#define H_ 16
#define DK_ 64
#define SCALE_ 0.125f
#define THETA_ 10000.0f
#define LOG2E_ 1.44269504f
#define THR_ 8.0f

typedef unsigned short ushort_t;
typedef __attribute__((ext_vector_type(8))) short bf16x8;   // 8 bf16 (4 VGPRs)
typedef __attribute__((ext_vector_type(4))) float f32x4;    // MFMA C/D

__device__ __forceinline__ ushort_t f2bf(float f) {
    union { float f; unsigned u; } v; v.f = f;
    unsigned r = (v.u + 0x7FFFu + ((v.u >> 16) & 1u)) >> 16;   // RNE
    return (ushort_t)r;
}

// pack bf16(lo),bf16(hi) by TRUNCATION: 1 v_perm_b32
__device__ __forceinline__ unsigned permpk(float lo, float hi) {
    return __builtin_amdgcn_perm(__float_as_uint(hi), __float_as_uint(lo), 0x07060302u);
}

// Vt swizzle (row in 0..63): XOR of low-3 chunk bits; same on write & read
__device__ __forceinline__ int vswz(int row) { return (row & 7) ^ ((row >> 3) & 3); }

#define GLOAD_LDS16(gptr, lptr)                                                   \
    __builtin_amdgcn_global_load_lds(                                             \
        (const __attribute__((address_space(1))) unsigned int*)(gptr),            \
        (__attribute__((address_space(3))) unsigned int*)(lptr), 16, 0, 0)

// ---------------------------------------------------------------------------
// Fused prep: fp32->bf16 casts (x + 4 weights) + RoPE table, one dispatch.
// ---------------------------------------------------------------------------
__global__ __launch_bounds__(256) void cast_all(const float* __restrict__ x,
                                                const float* __restrict__ W0,
                                                const float* __restrict__ W1,
                                                const float* __restrict__ W2,
                                                const float* __restrict__ W3,
                                                const int* __restrict__ pos,
                                                ushort_t* __restrict__ Xb,
                                                ushort_t* __restrict__ Wb,
                                                float2* __restrict__ tab) {
    const int bid = blockIdx.x;
    if (bid >= 12288) {                       // rope table
        int i = (bid - 12288) * 256 + threadIdx.x;   // 0..65535
        int s = i >> 5, p = i & 31;
        float freq = powf(THETA_, -2.0f * (float)p / 64.0f);
        float a = (float)pos[s] * freq;
        tab[i] = make_float2(cosf(a), sinf(a));
        return;
    }
    const float* src;
    ushort_t* dst;
    int i;
    if (bid < 8192) {
        src = x; dst = Xb;
        i = bid * 1024 + threadIdx.x * 4;
    } else {
        const int seg = (bid - 8192) >> 10;          // 0..3
        const int lb  = (bid - 8192) & 1023;
        src = (seg == 0) ? W0 : (seg == 1) ? W1 : (seg == 2) ? W2 : W3;
        dst = Wb + (size_t)seg * (D_ * D_);
        i = lb * 1024 + threadIdx.x * 4;
    }
    float4 v = *reinterpret_cast<const float4*>(src + i);
    unsigned lo = (unsigned)f2bf(v.x) | ((unsigned)f2bf(v.y) << 16);
    unsigned hi = (unsigned)f2bf(v.z) | ((unsigned)f2bf(v.w) << 16);
    uint2 u; u.x = lo; u.y = hi;
    *reinterpret_cast<uint2*>(dst + i) = u;
}

// ---------------------------------------------------------------------------
// bf16 MFMA GEMM, BK=64 + swizzled K-staging — R16 verbatim (verified win).
// MODE 0: fp32 Y[m*D+n]  MODE 1: bf16 Y[b,h,s,dk]  MODE 2: MODE1 + RoPE*qscale
// ---------------------------------------------------------------------------
template <int MODE>
__global__ __launch_bounds__(256) void gemm_bf16(const ushort_t* __restrict__ A,
                                                 const ushort_t* __restrict__ W,
                                                 const float2* __restrict__ tab,
                                                 float qscale,
                                                 float* __restrict__ outF,
                                                 ushort_t* __restrict__ outB) {
    __shared__ ushort_t Asl[128 * 64];
    __shared__ ushort_t Bsl[128 * 64];

    const int t = threadIdx.x;
    const int lane = t & 63;
    const int w = t >> 6;
    const int lr = lane & 15;
    const int lg = lane >> 4;

    const int bid = blockIdx.x;
    const int swz = (bid & 7) * 64 + (bid >> 3);
    const int m0 = (swz >> 3) * 128;
    const int n0 = (swz & 7) * 128;

    const int wr = w >> 1;
    const int wc = w & 1;

    f32x4 acc[4][4] = {};

    for (int k0 = 0; k0 < D_; k0 += 64) {
#pragma unroll
        for (int it = 0; it < 4; ++it) {
            const int slot = it * 256 + t;
            const int row = slot >> 3;
            const int cs = (slot & 7) ^ (row & 7);
            GLOAD_LDS16(A + (size_t)(m0 + row) * D_ + k0 + cs * 8, Asl + slot * 8);
            GLOAD_LDS16(W + (size_t)(n0 + row) * D_ + k0 + cs * 8, Bsl + slot * 8);
        }
        __syncthreads();

#pragma unroll
        for (int kk = 0; kk < 2; ++kk) {
            bf16x8 af[4], bfr[4];
#pragma unroll
            for (int x = 0; x < 4; ++x) {
                const int ra = wr * 64 + x * 16 + lr;
                const int rb = wc * 64 + x * 16 + lr;
                const int ch = (kk * 4 + lg) ^ (lr & 7);
                af[x]  = *reinterpret_cast<const bf16x8*>((char*)Asl + ra * 128 + (ch << 4));
                bfr[x] = *reinterpret_cast<const bf16x8*>((char*)Bsl + rb * 128 + (ch << 4));
            }
#pragma unroll
            for (int mi = 0; mi < 4; ++mi)
#pragma unroll
                for (int ni = 0; ni < 4; ++ni)
                    acc[mi][ni] = __builtin_amdgcn_mfma_f32_16x16x32_bf16(af[mi], bfr[ni], acc[mi][ni], 0, 0, 0);
        }
        __syncthreads();
    }

#pragma unroll
    for (int mi = 0; mi < 4; ++mi) {
#pragma unroll
        for (int r = 0; r < 4; ++r) {
            const int m = m0 + wr * 64 + mi * 16 + lg * 4 + r;
            const int bb = m >> 11;
            const int s = m & (S_ - 1);
#pragma unroll
            for (int ni = 0; ni < 4; ++ni) {
                const int n = n0 + wc * 64 + ni * 16 + lr;
                float v = acc[mi][ni][r];
                if (MODE == 0) {
                    outF[(size_t)m * D_ + n] = v;
                } else {
                    const int h = n >> 6, dk = n & 63;
                    if (MODE == 2) {
                        v *= qscale;
                        const float2 cs = tab[s * 32 + (dk >> 1)];
                        const float part = __shfl_xor(v, 1, 64);
                        v = (dk & 1) ? fmaf(v, cs.x, part * cs.y)
                                     : fmaf(v, cs.x, -part * cs.y);
                    }
                    outB[(((size_t)bb * H_ + h) * S_ + s) * DK_ + dk] = f2bf(v);
                }
            }
        }
    }
}

// ---------------------------------------------------------------------------
// MFMA flash attention v11 (causal) — R18 verbatim (72.6 us proven twice).
// Single barrier per KV tile: Vt double-buffered (Vt[kt&1]); the next tile's
// barrier publishes the new Vt and drains the K prefetch issued after the
// previous one. 48KB LDS, 2 blocks/CU, VGPR 60, occ ~36%.
// ---------------------------------------------------------------------------
__global__ __launch_bounds__(512) void attn_mfma(const ushort_t* __restrict__ Q,
                                                 const ushort_t* __restrict__ K,
                                                 const ushort_t* __restrict__ V,
                                                 ushort_t* __restrict__ O) {
    __shared__ ushort_t Ks[2][64 * 64];
    __shared__ ushort_t Vt[2][64 * 64];
    __shared__ ushort_t Pl[128 * 64];

    const int t = threadIdx.x;
    const int lane = t & 63;
    const int w = t >> 6;           // 0..7
    const int lr = lane & 15;
    const int lg = lane >> 4;

    const int bid = blockIdx.x;
    const int swz = (bid & 7) * 64 + (bid >> 3);
    const int bh = swz >> 3;
    const int p  = swz & 7;

    const ushort_t* Kbase = K + (size_t)bh * S_ * DK_;
    const ushort_t* Vbase = V + (size_t)bh * S_ * DK_;
    const int bb = bh >> 4, h = bh & 15;

    const int krow = t >> 3;                 // 0..63
    const int kc16 = (t & 7) ^ (krow & 7);
    const int dk8 = (t & 7) * 8;
    const int kv2 = ((t >> 3) & 31) * 2;

    bf16x8 ones;
#pragma unroll
    for (int j = 0; j < 8; ++j) ones[j] = (short)0x3F80;

    bf16x8 vpre0, vpre1;
    int kcur = 0;

    for (int ph = 0; ph < 2; ++ph) {
        const int qt = ph ? (15 - p) : p;
        const int q0 = qt * 128;
        const int nt = 2 * qt + 2;          // always even

        const ushort_t* Qbase = Q + ((size_t)bh * S_ + q0 + w * 16) * DK_;
        bf16x8 qf[2];
#pragma unroll
        for (int kf = 0; kf < 2; ++kf)
            qf[kf] = *reinterpret_cast<const bf16x8*>(
                Qbase + (size_t)lr * DK_ + kf * 32 + lg * 8);

        f32x4 acc[4] = {};
        f32x4 accl = {};
        float mrow = -INFINITY;

        // ---- prologue: K(0) -> Ks[kcur]; V(0) -> regs; drain + phase fence ----
        GLOAD_LDS16(Kbase + (size_t)krow * DK_ + kc16 * 8, &Ks[kcur][t * 8]);
        if (t < 256) {
            const ushort_t* Vsrc = Vbase + (size_t)kv2 * DK_ + dk8;
            vpre0 = *reinterpret_cast<const bf16x8*>(Vsrc);
            vpre1 = *reinterpret_cast<const bf16x8*>(Vsrc + DK_);
        }
        __syncthreads();

        for (int kt = 0; kt < nt; ++kt) {
            const int vcur = kt & 1;

            // ---- write V(kt) regs -> Vt[vcur] (transposed, swizzled) ----
            if (t < 256) {
                const unsigned* aw = reinterpret_cast<const unsigned*>(&vpre0);
                const unsigned* bw = reinterpret_cast<const unsigned*>(&vpre1);
#pragma unroll
                for (int j = 0; j < 8; ++j) {
                    const int row = dk8 + j;
                    const unsigned sel = (j & 1) ? 0x07060302u : 0x05040100u;
                    const unsigned pk = __builtin_amdgcn_perm(bw[j >> 1], aw[j >> 1], sel);
                    *reinterpret_cast<unsigned*>(
                        (char*)Vt[vcur] + row * 128 + ((kv2 * 2) ^ (vswz(row) << 4))) = pk;
                }
            }
            __syncthreads();    // THE barrier: publishes Vt[vcur]+drains K(kt)

            // ---- prefetches (in flight until next barrier) ----
            if (kt + 1 < nt) {
                const ushort_t* Ksrc = Kbase + (size_t)(kt + 1) * 64 * DK_;
                GLOAD_LDS16(Ksrc + (size_t)krow * DK_ + kc16 * 8, &Ks[kcur ^ 1][t * 8]);
                if (t < 256) {
                    const ushort_t* Vsrc = Vbase + (size_t)((kt + 1) * 64 + kv2) * DK_ + dk8;
                    vpre0 = *reinterpret_cast<const bf16x8*>(Vsrc);
                    vpre1 = *reinterpret_cast<const bf16x8*>(Vsrc + DK_);
                }
            }

            // ---- sT = K Q ----
            bf16x8 kb[4][2];
#pragma unroll
            for (int nf = 0; nf < 4; ++nf)
#pragma unroll
                for (int kf = 0; kf < 2; ++kf)
                    kb[nf][kf] = *reinterpret_cast<const bf16x8*>(
                        (char*)Ks[kcur] + (nf * 16 + lr) * 128 + (((kf * 4 + lg) ^ (lr & 7)) << 4));

            f32x4 sT[4];
#pragma unroll
            for (int nf = 0; nf < 4; ++nf) {
                f32x4 z = {};
                z = __builtin_amdgcn_mfma_f32_16x16x32_bf16(kb[nf][0], qf[0], z, 0, 0, 0);
                z = __builtin_amdgcn_mfma_f32_16x16x32_bf16(kb[nf][1], qf[1], z, 0, 0, 0);
                sT[nf] = z;
            }

            if (kt >= nt - 2) {
                const int q = q0 + w * 16 + lr;
#pragma unroll
                for (int nf = 0; nf < 4; ++nf)
#pragma unroll
                    for (int r = 0; r < 4; ++r) {
                        const int kv = kt * 64 + nf * 16 + lg * 4 + r;
                        if (kv > q) sT[nf][r] = -INFINITY;
                    }
            }

            {
                float m4 = -INFINITY;
#pragma unroll
                for (int nf = 0; nf < 4; ++nf)
#pragma unroll
                    for (int r = 0; r < 4; ++r) m4 = fmaxf(m4, sT[nf][r]);
                m4 = fmaxf(m4, __shfl_xor(m4, 16, 64));
                m4 = fmaxf(m4, __shfl_xor(m4, 32, 64));
                if (m4 > mrow + THR_) {
                    const float corr = __builtin_amdgcn_exp2f(mrow - m4);
                    mrow = m4;
#pragma unroll
                    for (int r = 0; r < 4; ++r) accl[r] *= corr;
#pragma unroll
                    for (int df = 0; df < 4; ++df)
#pragma unroll
                        for (int r = 0; r < 4; ++r) acc[df][r] *= corr;
                }
            }

            const int prow = w * 16 + lr;
            char* prowp = (char*)Pl + prow * 128;
#pragma unroll
            for (int nf = 0; nf < 4; ++nf) {
                const float p0 = __builtin_amdgcn_exp2f(sT[nf][0] - mrow);
                const float p1 = __builtin_amdgcn_exp2f(sT[nf][1] - mrow);
                const float p2 = __builtin_amdgcn_exp2f(sT[nf][2] - mrow);
                const float p3 = __builtin_amdgcn_exp2f(sT[nf][3] - mrow);
                uint2 pk;
                pk.x = permpk(p0, p1);
                pk.y = permpk(p2, p3);
                const int chunk = (nf * 2 + (lg >> 1)) ^ (lr & 7);
                *reinterpret_cast<uint2*>(prowp + (chunk << 4) + (lg & 1) * 8) = pk;
            }

            bf16x8 pfr[2];
#pragma unroll
            for (int kf = 0; kf < 2; ++kf)
                pfr[kf] = *reinterpret_cast<const bf16x8*>(
                    (char*)Pl + prow * 128 + (((kf * 4 + lg) ^ (lr & 7)) << 4));

            bf16x8 vtf[4][2];
#pragma unroll
            for (int df = 0; df < 4; ++df)
#pragma unroll
                for (int kf = 0; kf < 2; ++kf)
                    vtf[df][kf] = *reinterpret_cast<const bf16x8*>(
                        (char*)Vt[vcur] + (df * 16 + lr) * 128 + (((kf * 4 + lg) ^ vswz(df * 16 + lr)) << 4));

#pragma unroll
            for (int kf = 0; kf < 2; ++kf)
                accl = __builtin_amdgcn_mfma_f32_16x16x32_bf16(ones, pfr[kf], accl, 0, 0, 0);
#pragma unroll
            for (int df = 0; df < 4; ++df)
#pragma unroll
                for (int kf = 0; kf < 2; ++kf)
                    acc[df] = __builtin_amdgcn_mfma_f32_16x16x32_bf16(vtf[df][kf], pfr[kf], acc[df], 0, 0, 0);

            kcur ^= 1;          // no end-of-tile barrier (Vt dbuf + next B1)
        }
        kcur = 0;

        const float inv = 1.0f / accl[0];
        const int q = q0 + w * 16 + lr;
        ushort_t* Orow = O + ((size_t)bb * S_ + q) * D_ + h * DK_;
#pragma unroll
        for (int df = 0; df < 4; ++df) {
            unsigned lo = (unsigned)f2bf(acc[df][0] * inv) | ((unsigned)f2bf(acc[df][1] * inv) << 16);
            unsigned hi = (unsigned)f2bf(acc[df][2] * inv) | ((unsigned)f2bf(acc[df][3] * inv) << 16);
            *reinterpret_cast<unsigned*>(Orow + df * 16 + lg * 4)     = lo;
            *reinterpret_cast<unsigned*>(Orow + df * 16 + lg * 4 + 2) = hi;
        }
    }
}

// ---------------------------------------------------------------------------
// Launch: 6 dispatches
// ---------------------------------------------------------------------------
extern "C" void kernel_launch(void* const* d_in, const int* in_sizes, int n_in,
                              void* d_out, int out_size, void* d_ws, size_t ws_size,
                              hipStream_t stream) {
    const float* x  = (const float*)d_in[0];
    const int*   tp = (const int*)d_in[1];
    const float* Wq = (const float*)d_in[2];
    const float* Wk = (const float*)d_in[3];
    const float* Wv = (const float*)d_in[4];
    const float* Wo = (const float*)d_in[5];
    float* out = (float*)d_out;

    char* ws = (char*)d_ws;
    ushort_t* Xb  = (ushort_t*)(ws);
    ushort_t* Wqb = (ushort_t*)(ws + (16ull << 20));   // Wq|Wk|Wv|Wo contiguous
    ushort_t* Wkb = (ushort_t*)(ws + (18ull << 20));
    ushort_t* Wvb = (ushort_t*)(ws + (20ull << 20));
    ushort_t* Wob = (ushort_t*)(ws + (22ull << 20));
    ushort_t* Qb  = (ushort_t*)(ws + (24ull << 20));
    ushort_t* Kb  = (ushort_t*)(ws + (40ull << 20));
    ushort_t* Vb  = (ushort_t*)(ws + (56ull << 20));
    ushort_t* Ao  = (ushort_t*)(ws + (72ull << 20));
    float2*   tab = (float2*)(ws + (88ull << 20));

    cast_all<<<8192 + 4096 + 256, 256, 0, stream>>>(x, Wq, Wk, Wv, Wo, tp, Xb, Wqb, tab);

    gemm_bf16<2><<<512, 256, 0, stream>>>(Xb, Wqb, tab, SCALE_ * LOG2E_, nullptr, Qb);
    gemm_bf16<2><<<512, 256, 0, stream>>>(Xb, Wkb, tab, 1.0f, nullptr, Kb);
    gemm_bf16<1><<<512, 256, 0, stream>>>(Xb, Wvb, tab, 1.0f, nullptr, Vb);

    attn_mfma<<<512, 512, 0, stream>>>(Qb, Kb, Vb, Ao);

    gemm_bf16<0><<<512, 256, 0, stream>>>(Ao, Wob, tab, 1.0f, out, nullptr);
}